// Round 6
// baseline (102.363 us; speedup 1.0000x reference)
//
#include <hip/hip_runtime.h>

// CTC batch cost, B=256 T=512 C=256 L=64 (S=129).
// One block/batch, 2 waves: wave0 = forward DP t=0..255, wave1 = backward DP
// t=511..256. Lane l owns states {2l,2l+1}; state 128 carried as 'ex'.
// FP64 LINEAR-domain DP: no per-step transcendentals, no renormalization
// (f64 range covers the ~2^-550 worst-case state magnitudes; R5's f32+renorm
// lost mass to denormal flush). Cross-lane via paired 32-bit DPP wave shifts.
// Cut-combine in log2 domain (R4 lesson: per-side maxima are anti-aligned
// across states, so linear cross-products underflow).

constexpr int Bc = 256;
constexpr int Tc = 512;
constexpr int Cc = 256;
constexpr int Lc = 64;

#define EPSF (1e-7f)
#define NEGF (-1e30f)

__device__ __forceinline__ float flog2(float x) {
    float r; asm("v_log_f32 %0, %1" : "=v"(r) : "v"(x)); return r;
}
__device__ __forceinline__ float fexp2(float x) {
    float r; asm("v_exp_f32 %0, %1" : "=v"(r) : "v"(x)); return r;
}
// log2(2^a + 2^b); safe for NEGF sentinels
__device__ __forceinline__ float lse2(float a, float b) {
    float m = fmaxf(a, b);
    float d = fminf(a, b) - m;
    return m + flog2(1.f + fexp2(d));
}
// log2 of a positive double via exponent extraction + f32 mantissa log.
__device__ __forceinline__ float dlog2(double x) {
    if (!(x > 1e-300)) return NEGF;             // 0 / dead state -> -inf proxy
    const int hb = __double2hiint(x);
    const int lb = __double2loint(x);
    const int e  = ((hb >> 20) & 0x7FF) - 1022;           // x = m * 2^e
    const double m = __hiloint2double((hb & 0x800FFFFF) | (1022 << 20), lb);
    return flog2((float)m) + (float)e;                    // m in [0.5, 1)
}
// double wave shifts via paired 32-bit DPP; 'old' fills the boundary lane.
// lane i <- lane i-1; lane 0 <- old   (row_shr:1, verified R3)
__device__ __forceinline__ double dpp_up1_d(double old, double src) {
    const int rl = __builtin_amdgcn_update_dpp(
        __double2loint(old), __double2loint(src), 0x138, 0xF, 0xF, false);
    const int rh = __builtin_amdgcn_update_dpp(
        __double2hiint(old), __double2hiint(src), 0x138, 0xF, 0xF, false);
    return __hiloint2double(rh, rl);
}
// lane i <- lane i+1; lane 63 <- old  (row_shl:1, verified R3)
__device__ __forceinline__ double dpp_dn1_d(double old, double src) {
    const int rl = __builtin_amdgcn_update_dpp(
        __double2loint(old), __double2loint(src), 0x130, 0xF, 0xF, false);
    const int rh = __builtin_amdgcn_update_dpp(
        __double2hiint(old), __double2hiint(src), 0x130, 0xF, 0xF, false);
    return __hiloint2double(rh, rl);
}
__device__ __forceinline__ float rdlane(float v, int idx) {
    return __int_as_float(__builtin_amdgcn_readlane(__float_as_int(v), idx));
}

__global__ __launch_bounds__(128, 1) void ctc_fb_kernel(
        const int* __restrict__ y_true,
        const float* __restrict__ y_pred,
        float* __restrict__ out)
{
    const int b    = blockIdx.x;
    const int lane = threadIdx.x & 63;
    const int wid  = threadIdx.x >> 6;

    __shared__ float Cl[64], Ch[64], Cex;   // log2-domain C(s) from bwd wave

    const float* __restrict__ base = y_pred + (size_t)b * Tc * Cc;

    // Blank-channel gathers, EPS pre-added. Wave0: t=0..255, wave1: 256..511.
    const int tB0 = wid ? 256 : 0;
    const float bv0 = base[(size_t)(tB0 +       lane) * Cc + (Cc - 1)] + EPSF;
    const float bv1 = base[(size_t)(tB0 +  64 + lane) * Cc + (Cc - 1)] + EPSF;
    const float bv2 = base[(size_t)(tB0 + 128 + lane) * Cc + (Cc - 1)] + EPSF;
    const float bv3 = base[(size_t)(tB0 + 192 + lane) * Cc + (Cc - 1)] + EPSF;

    const int lab  = y_true[b * Lc + lane];      // label for state 2*lane+1
    const int labp = __shfl_up(lab, 1);
    const int labn = __shfl_down(lab, 1);
    const float* __restrict__ rowL = base + lab;

    double lo = 0.0, hi = 0.0, ex = 0.0;

    if (wid == 0) {
        // ---------------- forward: t = 0 .. 255 ----------------
        const bool allow = (lane >= 1) && (lab != labp);
        float p[15], A0[16], A1[16], A2[16];
        #pragma unroll
        for (int i = 0; i < 15; ++i) p[i]  = rowL[(size_t)(1 + i) * Cc];
        #pragma unroll
        for (int i = 0; i < 16; ++i) A0[i] = rowL[(size_t)(16 + i) * Cc];
        #pragma unroll
        for (int i = 0; i < 16; ++i) A1[i] = rowL[(size_t)(32 + i) * Cc];

        // t=0 init: only states 0,1 reachable (lane 0)
        lo = (lane == 0) ? (double)rdlane(bv0, 0) : 0.0;
        hi = (lane == 0) ? (double)(rowL[0] + EPSF) : 0.0;

        auto step = [&](float pBf, float pLf) {
            const double pB = (double)pBf, pL = (double)pLf;
            const double prevHi = dpp_up1_d(0.0, hi);
            const double sk  = allow ? prevHi : 0.0;
            const double nlo = (lo + prevHi) * pB;
            const double nhi = (hi + lo + sk) * pL;
            ex = (ex + hi) * pB;      // real only at lane 63 (state 127->128)
            hi = nhi; lo = nlo;
        };
        // prologue t = 1..15 (blank block 0)
        #pragma unroll
        for (int i = 0; i < 15; ++i) step(rdlane(bv0, 1 + i), p[i] + EPSF);

        float A2b[16];
        #pragma unroll
        for (int i = 0; i < 16; ++i) A2b[i] = rowL[(size_t)(48 + i) * Cc];
        #pragma unroll
        for (int i = 0; i < 16; ++i) A2[i] = A2b[i];

        auto chunk = [&](float (&buf)[16], int cs) {   // steps t = cs..cs+15
            float bv = bv0;
            bv = (cs >= 64)  ? bv1 : bv;
            bv = (cs >= 128) ? bv2 : bv;
            bv = (cs >= 192) ? bv3 : bv;
            const int ib = cs & 63;
            #pragma unroll
            for (int i = 0; i < 16; ++i) step(rdlane(bv, ib + i), buf[i] + EPSF);
        };
        auto load = [&](float (&buf)[16], int t0) {
            #pragma unroll
            for (int i = 0; i < 16; ++i) {
                int t = t0 + i; t = t > 255 ? 255 : t;
                buf[i] = rowL[(size_t)t * Cc];
            }
        };
        for (int it = 0; it < 5; ++it) {
            const int t0 = 16 + 48 * it;
            chunk(A0, t0);      if (it < 4) load(A0, t0 + 48);
            chunk(A1, t0 + 16); if (it < 4) load(A1, t0 + 64);
            chunk(A2, t0 + 32); if (it < 4) load(A2, t0 + 80);
        }
        // states now = alpha_255 (exact scale, f64)
    } else {
        // ---------------- backward: t = 511 .. 256 ----------------
        const bool allow = (lane < 63) && (labn != lab);
        float p[15], A0[16], A1[16], A2[16];
        #pragma unroll
        for (int i = 0; i < 15; ++i) p[i]  = rowL[(size_t)(510 - i) * Cc];
        #pragma unroll
        for (int i = 0; i < 16; ++i) A0[i] = rowL[(size_t)(495 - i) * Cc];
        #pragma unroll
        for (int i = 0; i < 16; ++i) A1[i] = rowL[(size_t)(479 - i) * Cc];

        // t=511 init: beta(128)=pB (uniform), beta(127)=pL (lane63)
        ex = (double)rdlane(bv3, 63);
        hi = (lane == 63) ? (double)(rowL[(size_t)511 * Cc] + EPSF) : 0.0;
        lo = 0.0;

        auto step = [&](float pBf, float pLf) {
            const double pB = (double)pBf, pL = (double)pLf;
            const double nlo_s = dpp_dn1_d(ex, lo);    // B(2l+2); lane63 <- ex
            const double nhi_s = dpp_dn1_d(0.0, hi);   // B(2l+3); lane63 <- 0
            const double sk = allow ? nhi_s : 0.0;
            const double l2 = (lo + hi) * pB;
            const double h2 = (hi + nlo_s + sk) * pL;
            ex = ex * pB;
            lo = l2; hi = h2;
        };
        // prologue t = 510..496 (blank block 3, idx 62-i)
        #pragma unroll
        for (int i = 0; i < 15; ++i) step(rdlane(bv3, 62 - i), p[i] + EPSF);

        float A2b[16];
        #pragma unroll
        for (int i = 0; i < 16; ++i) A2b[i] = rowL[(size_t)(463 - i) * Cc];
        #pragma unroll
        for (int i = 0; i < 16; ++i) A2[i] = A2b[i];

        auto chunk = [&](float (&buf)[16], int cs) {   // steps t = cs..cs-15
            const int cb = cs - 256;
            float bv = bv0;
            bv = (cb >= 64)  ? bv1 : bv;
            bv = (cb >= 128) ? bv2 : bv;
            bv = (cb >= 192) ? bv3 : bv;
            const int ib = cs & 63;
            #pragma unroll
            for (int i = 0; i < 16; ++i) step(rdlane(bv, ib - i), buf[i] + EPSF);
        };
        auto load = [&](float (&buf)[16], int t0) {
            #pragma unroll
            for (int i = 0; i < 16; ++i) {
                int t = t0 - i; t = t < 256 ? 256 : t;
                buf[i] = rowL[(size_t)t * Cc];
            }
        };
        for (int it = 0; it < 5; ++it) {
            const int t0 = 495 - 48 * it;
            chunk(A0, t0);      if (it < 4) load(A0, t0 - 48);
            chunk(A1, t0 - 16); if (it < 4) load(A1, t0 - 64);
            chunk(A2, t0 - 32); if (it < 4) load(A2, t0 - 80);
        }
        // combine half-step at the cut (transition only, no emission):
        // C(s) = B(s) + B(s+1) + allowB(s)*B(s+2), stored in log2 domain.
        const double nlo_s = dpp_dn1_d(ex, lo);
        const double nhi_s = dpp_dn1_d(0.0, hi);
        const double sk = allow ? nhi_s : 0.0;
        Cl[lane] = dlog2(lo + hi);                 // C(2l)
        Ch[lane] = dlog2(hi + nlo_s + sk);         // C(2l+1)
        if (lane == 63) Cex = dlog2(ex);           // C(128)
    }

    __syncthreads();

    if (wid == 0) {
        // log2-domain combine: total = sum_s alpha_255(s) * C(s)
        const float w1 = dlog2(lo) + Cl[lane];
        const float w2 = dlog2(hi) + Ch[lane];
        float w = lse2(w1, w2);
        if (lane == 63) w = lse2(w, dlog2(ex) + Cex);
        #pragma unroll
        for (int off = 32; off; off >>= 1) w = lse2(w, __shfl_xor(w, off));
        if (lane == 0)
            out[b] = -0.69314718055994530942f * w;    // ln2 * log2 -> ln
    }
}

extern "C" void kernel_launch(void* const* d_in, const int* in_sizes, int n_in,
                              void* d_out, int out_size, void* d_ws, size_t ws_size,
                              hipStream_t stream) {
    const int*   y_true = (const int*)d_in[0];
    const float* y_pred = (const float*)d_in[1];
    float*       out    = (float*)d_out;
    ctc_fb_kernel<<<dim3(Bc), dim3(128), 0, stream>>>(y_true, y_pred, out);
}

// Round 7
// 34.572 us; speedup vs baseline: 2.9608x; 2.9608x over previous
//
#include <hip/hip_runtime.h>

// CTC batch cost, B=256 T=512 C=256 L=64 (S=129).
// One block/batch, 2 waves: wave0 = forward DP t=0..255, wave1 = backward DP
// t=511..256 (local step u, global row = 511-u). Lane l owns states {2l,2l+1};
// state 128 carried as 'ex'. FP64 linear-domain DP (R6: absmax 0.0), no renorm.
// R7: all per-step probabilities staged through a 16-slot LDS row ring filled
// by global_load_lds (1 KB row = one dwordx4 DMA), counted vmcnt waits,
// 4-step-ahead LDS->named-register prefetch. No register arrays -> no scratch
// spill (R6 lesson: VGPR=52 + WRITE_SIZE=3.9MB proved the gather buffers
// lived in scratch). Cut-combine in log2 domain (R4 lesson).

constexpr int Bc = 256;
constexpr int Tc = 512;
constexpr int Cc = 256;
constexpr int Lc = 64;

#define EPSF (1e-7f)
#define NEGF (-1e30f)

__device__ __forceinline__ float flog2(float x) {
    float r; asm("v_log_f32 %0, %1" : "=v"(r) : "v"(x)); return r;
}
__device__ __forceinline__ float fexp2(float x) {
    float r; asm("v_exp_f32 %0, %1" : "=v"(r) : "v"(x)); return r;
}
// log2(2^a + 2^b); safe for NEGF sentinels
__device__ __forceinline__ float lse2(float a, float b) {
    float m = fmaxf(a, b);
    float d = fminf(a, b) - m;
    return m + flog2(1.f + fexp2(d));
}
// log2 of a positive double via exponent extraction + f32 mantissa log.
__device__ __forceinline__ float dlog2(double x) {
    if (!(x > 1e-300)) return NEGF;
    const int hb = __double2hiint(x);
    const int lb = __double2loint(x);
    const int e  = ((hb >> 20) & 0x7FF) - 1022;
    const double m = __hiloint2double((hb & 0x800FFFFF) | (1022 << 20), lb);
    return flog2((float)m) + (float)e;            // m in [0.5, 1)
}
// double wave shifts via paired 32-bit DPP; 'old' fills the boundary lane.
__device__ __forceinline__ double dpp_up1_d(double old, double src) {   // lane i <- i-1
    const int rl = __builtin_amdgcn_update_dpp(
        __double2loint(old), __double2loint(src), 0x138, 0xF, 0xF, false);
    const int rh = __builtin_amdgcn_update_dpp(
        __double2hiint(old), __double2hiint(src), 0x138, 0xF, 0xF, false);
    return __hiloint2double(rh, rl);
}
__device__ __forceinline__ double dpp_dn1_d(double old, double src) {   // lane i <- i+1
    const int rl = __builtin_amdgcn_update_dpp(
        __double2loint(old), __double2loint(src), 0x130, 0xF, 0xF, false);
    const int rh = __builtin_amdgcn_update_dpp(
        __double2hiint(old), __double2hiint(src), 0x130, 0xF, 0xF, false);
    return __hiloint2double(rh, rl);
}
// async global->LDS: lane l writes bytes [16l,16l+16) of the slot.
__device__ __forceinline__ void stage16(const float* g, float* l) {
    __builtin_amdgcn_global_load_lds(
        (const __attribute__((address_space(1))) void*)g,
        (__attribute__((address_space(3))) void*)l, 16, 0, 0);
}

__global__ __launch_bounds__(128, 1) void ctc_fb_kernel(
        const int* __restrict__ y_true,
        const float* __restrict__ y_pred,
        float* __restrict__ out)
{
    const int b    = blockIdx.x;
    const int lane = threadIdx.x & 63;
    const int wid  = threadIdx.x >> 6;

    __shared__ float ring[2][16][Cc];        // 32 KB: per-wave 16-row ring
    __shared__ float Cl[64], Ch[64], CexS;

    const float* __restrict__ bbase = y_pred + (size_t)b * Tc * Cc;
    const int lab  = y_true[b * Lc + lane];
    const int labp = __shfl_up(lab, 1);
    const int labn = __shfl_down(lab, 1);

    float (*slots)[Cc] = ring[wid];

    // local row u -> global row: fwd u, bwd 511-u
#define GROW(u) (bbase + (size_t)(wid ? (Tc - 1 - (u)) : (u)) * Cc)
#define STAGE(u) stage16(GROW(u) + lane * 4, &slots[(u) & 15][0])

    // prologue: stage local rows 0..11
    #pragma unroll
    for (int u = 0; u < 12; ++u) STAGE(u);
    asm volatile("s_waitcnt vmcnt(8)" ::: "memory");   // rows 0..3 landed

    float cL0 = slots[0][lab], cB0 = slots[0][Cc - 1];
    float cL1 = slots[1][lab], cB1 = slots[1][Cc - 1];
    float cL2 = slots[2][lab], cB2 = slots[2][Cc - 1];
    float cL3 = slots[3][lab], cB3 = slots[3][Cc - 1];

    double lo = 0.0, hi = 0.0, ex = 0.0;
    const bool allowF = (lane >= 1) && (lab != labp);
    const bool allowB = (lane < 63) && (labn != lab);

    auto stepF = [&](float pBf, float pLf) {
        const double pB = (double)pBf, pL = (double)pLf;
        const double prevHi = dpp_up1_d(0.0, hi);
        const double sk  = allowF ? prevHi : 0.0;
        const double nlo = (lo + prevHi) * pB;
        const double nhi = (hi + lo + sk) * pL;
        ex = (ex + hi) * pB;          // real only at lane 63 (state 127->128)
        hi = nhi; lo = nlo;
    };
    auto stepB = [&](float pBf, float pLf) {
        const double pB = (double)pBf, pL = (double)pLf;
        const double nlo_s = dpp_dn1_d(ex, lo);    // B(2l+2); lane63 <- ex
        const double nhi_s = dpp_dn1_d(0.0, hi);   // B(2l+3); lane63 <- 0
        const double sk = allowB ? nhi_s : 0.0;
        const double l2 = (lo + hi) * pB;
        const double h2 = (hi + nlo_s + sk) * pL;
        ex = ex * pB;
        lo = l2; hi = h2;
    };

    // ---- group 0 (peeled: row 0 is the DP init, not a transition) ----
    STAGE(12); STAGE(13); STAGE(14); STAGE(15);
    asm volatile("s_waitcnt vmcnt(8)" ::: "memory");   // rows <= 7 landed
    float nL0 = slots[4][lab], nB0 = slots[4][Cc - 1];
    float nL1 = slots[5][lab], nB1 = slots[5][Cc - 1];
    float nL2 = slots[6][lab], nB2 = slots[6][Cc - 1];
    float nL3 = slots[7][lab], nB3 = slots[7][Cc - 1];
    if (wid == 0) {
        lo = (lane == 0) ? (double)(cB0 + EPSF) : 0.0;   // alpha0(0)
        hi = (lane == 0) ? (double)(cL0 + EPSF) : 0.0;   // alpha0(1)
        stepF(cB1 + EPSF, cL1 + EPSF);
        stepF(cB2 + EPSF, cL2 + EPSF);
        stepF(cB3 + EPSF, cL3 + EPSF);
    } else {
        ex = (double)(cB0 + EPSF);                        // beta511(128)
        hi = (lane == 63) ? (double)(cL0 + EPSF) : 0.0;   // beta511(127)
        lo = 0.0;
        stepB(cB1 + EPSF, cL1 + EPSF);
        stepB(cB2 + EPSF, cL2 + EPSF);
        stepB(cB3 + EPSF, cL3 + EPSF);
    }
    cL0 = nL0; cB0 = nB0; cL1 = nL1; cB1 = nB1;
    cL2 = nL2; cB2 = nB2; cL3 = nL3; cB3 = nB3;

    // ---- main groups g = 1..63: steps 4g..4g+3 use rows 4g..4g+3 ----
    for (int g = 1; g < 64; ++g) {
        const int r0 = 4 * g + 12;
        if (r0 <= 255) { STAGE(r0); STAGE(r0 + 1); STAGE(r0 + 2); STAGE(r0 + 3); }
        // wait so that rows <= 4g+7 have landed (tail groups stage fewer rows)
        if (g <= 60)      asm volatile("s_waitcnt vmcnt(8)" ::: "memory");
        else if (g == 61) asm volatile("s_waitcnt vmcnt(4)" ::: "memory");
        else if (g == 62) asm volatile("s_waitcnt vmcnt(0)" ::: "memory");
        const int q = 4 * g + 4;                 // next-group rows (stale reads
        const int s0 = q & 15, s1 = (q + 1) & 15;        // past row 255 unused)
        const int s2 = (q + 2) & 15, s3 = (q + 3) & 15;
        nL0 = slots[s0][lab]; nB0 = slots[s0][Cc - 1];
        nL1 = slots[s1][lab]; nB1 = slots[s1][Cc - 1];
        nL2 = slots[s2][lab]; nB2 = slots[s2][Cc - 1];
        nL3 = slots[s3][lab]; nB3 = slots[s3][Cc - 1];
        if (wid == 0) {
            stepF(cB0 + EPSF, cL0 + EPSF);
            stepF(cB1 + EPSF, cL1 + EPSF);
            stepF(cB2 + EPSF, cL2 + EPSF);
            stepF(cB3 + EPSF, cL3 + EPSF);
        } else {
            stepB(cB0 + EPSF, cL0 + EPSF);
            stepB(cB1 + EPSF, cL1 + EPSF);
            stepB(cB2 + EPSF, cL2 + EPSF);
            stepB(cB3 + EPSF, cL3 + EPSF);
        }
        cL0 = nL0; cB0 = nB0; cL1 = nL1; cB1 = nB1;
        cL2 = nL2; cB2 = nB2; cL3 = nL3; cB3 = nB3;
    }

    // ---- cut combine: C(s) = B(s) + B(s+1) + allowB(s)*B(s+2), log2 domain
    if (wid == 1) {
        const double nlo_s = dpp_dn1_d(ex, lo);
        const double nhi_s = dpp_dn1_d(0.0, hi);
        const double sk = allowB ? nhi_s : 0.0;
        Cl[lane] = dlog2(lo + hi);
        Ch[lane] = dlog2(hi + nlo_s + sk);
        if (lane == 63) CexS = dlog2(ex);
    }
    __syncthreads();

    if (wid == 0) {
        const float w1 = dlog2(lo) + Cl[lane];
        const float w2 = dlog2(hi) + Ch[lane];
        float w = lse2(w1, w2);
        if (lane == 63) w = lse2(w, dlog2(ex) + CexS);
        #pragma unroll
        for (int off = 32; off; off >>= 1) w = lse2(w, __shfl_xor(w, off));
        if (lane == 0)
            out[b] = -0.69314718055994530942f * w;     // ln2 * log2 -> ln
    }
}

extern "C" void kernel_launch(void* const* d_in, const int* in_sizes, int n_in,
                              void* d_out, int out_size, void* d_ws, size_t ws_size,
                              hipStream_t stream) {
    const int*   y_true = (const int*)d_in[0];
    const float* y_pred = (const float*)d_in[1];
    float*       out    = (float*)d_out;
    ctc_fb_kernel<<<dim3(Bc), dim3(128), 0, stream>>>(y_true, y_pred, out);
}

// Round 8
// 31.858 us; speedup vs baseline: 3.2131x; 1.0852x over previous
//
#include <hip/hip_runtime.h>

// CTC batch cost, B=256 T=512 C=256 L=64 (S=129).
// One block/batch, 2 waves: wave0 = forward DP t=0..255, wave1 = backward DP
// t=511..256 (local row u -> global row 511-u). Lane l owns states {2l,2l+1};
// state 128 carried as 'ex'. FP64 linear-domain DP (R6/R7: absmax 0.0).
// R8: pipeline deepened -- 32-slot LDS row ring per wave (64 KB), 8 rows per
// group, steady 16-24 KB in flight per wave with counted vmcnt(16) waits
// (R7 lesson: 4-row groups + vmcnt(8) left the wave idle ~80% of each group).
// Cut-combine in log2 domain (R4 lesson: per-side maxima anti-aligned).

constexpr int Bc = 256;
constexpr int Tc = 512;
constexpr int Cc = 256;
constexpr int Lc = 64;

#define EPSF (1e-7f)
#define NEGF (-1e30f)

__device__ __forceinline__ float flog2(float x) {
    float r; asm("v_log_f32 %0, %1" : "=v"(r) : "v"(x)); return r;
}
__device__ __forceinline__ float fexp2(float x) {
    float r; asm("v_exp_f32 %0, %1" : "=v"(r) : "v"(x)); return r;
}
__device__ __forceinline__ float lse2(float a, float b) {
    float m = fmaxf(a, b);
    float d = fminf(a, b) - m;
    return m + flog2(1.f + fexp2(d));
}
// log2 of a positive double via exponent extraction + f32 mantissa log.
__device__ __forceinline__ float dlog2(double x) {
    if (!(x > 1e-300)) return NEGF;
    const int hb = __double2hiint(x);
    const int lb = __double2loint(x);
    const int e  = ((hb >> 20) & 0x7FF) - 1022;
    const double m = __hiloint2double((hb & 0x800FFFFF) | (1022 << 20), lb);
    return flog2((float)m) + (float)e;            // m in [0.5, 1)
}
// double wave shifts via paired 32-bit DPP; 'old' fills the boundary lane.
__device__ __forceinline__ double dpp_up1_d(double old, double src) {   // lane i <- i-1
    const int rl = __builtin_amdgcn_update_dpp(
        __double2loint(old), __double2loint(src), 0x138, 0xF, 0xF, false);
    const int rh = __builtin_amdgcn_update_dpp(
        __double2hiint(old), __double2hiint(src), 0x138, 0xF, 0xF, false);
    return __hiloint2double(rh, rl);
}
__device__ __forceinline__ double dpp_dn1_d(double old, double src) {   // lane i <- i+1
    const int rl = __builtin_amdgcn_update_dpp(
        __double2loint(old), __double2loint(src), 0x130, 0xF, 0xF, false);
    const int rh = __builtin_amdgcn_update_dpp(
        __double2hiint(old), __double2hiint(src), 0x130, 0xF, 0xF, false);
    return __hiloint2double(rh, rl);
}
// async global->LDS: lane l writes bytes [16l,16l+16) of the 1 KB slot.
__device__ __forceinline__ void stage16(const float* g, float* l) {
    __builtin_amdgcn_global_load_lds(
        (const __attribute__((address_space(1))) void*)g,
        (__attribute__((address_space(3))) void*)l, 16, 0, 0);
}

__global__ __launch_bounds__(128, 1) void ctc_fb_kernel(
        const int* __restrict__ y_true,
        const float* __restrict__ y_pred,
        float* __restrict__ out)
{
    const int b    = blockIdx.x;
    const int lane = threadIdx.x & 63;
    const int wid  = threadIdx.x >> 6;

    __shared__ float ring[2][32][Cc];        // 64 KB: per-wave 32-row ring
    __shared__ float Cl[64], Ch[64], CexS;

    const float* __restrict__ bbase = y_pred + (size_t)b * Tc * Cc;
    const int lab  = y_true[b * Lc + lane];
    const int labp = __shfl_up(lab, 1);
    const int labn = __shfl_down(lab, 1);

    float (*slots)[Cc] = ring[wid];

#define GROW(u) (bbase + (size_t)(wid ? (Tc - 1 - (u)) : (u)) * Cc)
#define STAGE(u) stage16(GROW(u) + lane * 4, &slots[(u) & 31][0])

    // prologue: stage local rows 0..23 (24 in flight)
    #pragma unroll
    for (int u = 0; u < 24; ++u) STAGE(u);
    asm volatile("s_waitcnt vmcnt(16)" ::: "memory");   // rows 0..7 landed

    float cB0, cB1, cB2, cB3, cB4, cB5, cB6, cB7;
    float cL0, cL1, cL2, cL3, cL4, cL5, cL6, cL7;
    float nB0, nB1, nB2, nB3, nB4, nB5, nB6, nB7;
    float nL0, nL1, nL2, nL3, nL4, nL5, nL6, nL7;

#define RDC(j) { cL##j = slots[j][lab]; cB##j = slots[j][Cc - 1]; }
    RDC(0) RDC(1) RDC(2) RDC(3) RDC(4) RDC(5) RDC(6) RDC(7)
#undef RDC

    double lo = 0.0, hi = 0.0, ex = 0.0;
    const bool allowF = (lane >= 1) && (lab != labp);
    const bool allowB = (lane < 63) && (labn != lab);

    auto stepF = [&](float pBf, float pLf) {
        const double pB = (double)pBf, pL = (double)pLf;
        const double prevHi = dpp_up1_d(0.0, hi);
        const double sk  = allowF ? prevHi : 0.0;
        const double nlo = (lo + prevHi) * pB;
        const double nhi = (hi + lo + sk) * pL;
        ex = (ex + hi) * pB;          // real only at lane 63 (state 127->128)
        hi = nhi; lo = nlo;
    };
    auto stepB = [&](float pBf, float pLf) {
        const double pB = (double)pBf, pL = (double)pLf;
        const double nlo_s = dpp_dn1_d(ex, lo);    // B(2l+2); lane63 <- ex
        const double nhi_s = dpp_dn1_d(0.0, hi);   // B(2l+3); lane63 <- 0
        const double sk = allowB ? nhi_s : 0.0;
        const double l2 = (lo + hi) * pB;
        const double h2 = (hi + nlo_s + sk) * pL;
        ex = ex * pB;
        lo = l2; hi = h2;
    };

    // main groups g=0..31: steps/rows 8g..8g+7 (g=0 peels row 0 as DP init)
    for (int g = 0; g < 32; ++g) {
        const int r0 = 8 * g + 24;
        if (g <= 28) {      // last staged row: g=28 -> rows 248..255
            STAGE(r0);     STAGE(r0 + 1); STAGE(r0 + 2); STAGE(r0 + 3);
            STAGE(r0 + 4); STAGE(r0 + 5); STAGE(r0 + 6); STAGE(r0 + 7);
        }
        // guarantee rows <= 8g+15 landed (exactly 16 newer rows outstanding)
        if (g <= 28)      asm volatile("s_waitcnt vmcnt(16)" ::: "memory");
        else if (g == 29) asm volatile("s_waitcnt vmcnt(8)"  ::: "memory");
        else if (g == 30) asm volatile("s_waitcnt vmcnt(0)"  ::: "memory");
        if (g < 31) {
            const int q = 8 * g + 8;             // next group's rows
#define RDN(j) { const int sl = (q + j) & 31; nL##j = slots[sl][lab]; nB##j = slots[sl][Cc - 1]; }
            RDN(0) RDN(1) RDN(2) RDN(3) RDN(4) RDN(5) RDN(6) RDN(7)
#undef RDN
        }
        if (wid == 0) {
            if (g == 0) {
                lo = (lane == 0) ? (double)(cB0 + EPSF) : 0.0;   // alpha0(0)
                hi = (lane == 0) ? (double)(cL0 + EPSF) : 0.0;   // alpha0(1)
            } else stepF(cB0 + EPSF, cL0 + EPSF);
            stepF(cB1 + EPSF, cL1 + EPSF); stepF(cB2 + EPSF, cL2 + EPSF);
            stepF(cB3 + EPSF, cL3 + EPSF); stepF(cB4 + EPSF, cL4 + EPSF);
            stepF(cB5 + EPSF, cL5 + EPSF); stepF(cB6 + EPSF, cL6 + EPSF);
            stepF(cB7 + EPSF, cL7 + EPSF);
        } else {
            if (g == 0) {
                ex = (double)(cB0 + EPSF);                        // beta511(128)
                hi = (lane == 63) ? (double)(cL0 + EPSF) : 0.0;   // beta511(127)
                lo = 0.0;
            } else stepB(cB0 + EPSF, cL0 + EPSF);
            stepB(cB1 + EPSF, cL1 + EPSF); stepB(cB2 + EPSF, cL2 + EPSF);
            stepB(cB3 + EPSF, cL3 + EPSF); stepB(cB4 + EPSF, cL4 + EPSF);
            stepB(cB5 + EPSF, cL5 + EPSF); stepB(cB6 + EPSF, cL6 + EPSF);
            stepB(cB7 + EPSF, cL7 + EPSF);
        }
        if (g < 31) {
            cB0 = nB0; cB1 = nB1; cB2 = nB2; cB3 = nB3;
            cB4 = nB4; cB5 = nB5; cB6 = nB6; cB7 = nB7;
            cL0 = nL0; cL1 = nL1; cL2 = nL2; cL3 = nL3;
            cL4 = nL4; cL5 = nL5; cL6 = nL6; cL7 = nL7;
        }
    }

    // ---- cut combine: C(s) = B(s) + B(s+1) + allowB(s)*B(s+2), log2 domain
    if (wid == 1) {
        const double nlo_s = dpp_dn1_d(ex, lo);
        const double nhi_s = dpp_dn1_d(0.0, hi);
        const double sk = allowB ? nhi_s : 0.0;
        Cl[lane] = dlog2(lo + hi);
        Ch[lane] = dlog2(hi + nlo_s + sk);
        if (lane == 63) CexS = dlog2(ex);
    }
    __syncthreads();

    if (wid == 0) {
        const float w1 = dlog2(lo) + Cl[lane];
        const float w2 = dlog2(hi) + Ch[lane];
        float w = lse2(w1, w2);
        if (lane == 63) w = lse2(w, dlog2(ex) + CexS);
        #pragma unroll
        for (int off = 32; off; off >>= 1) w = lse2(w, __shfl_xor(w, off));
        if (lane == 0)
            out[b] = -0.69314718055994530942f * w;     // ln2 * log2 -> ln
    }
}

extern "C" void kernel_launch(void* const* d_in, const int* in_sizes, int n_in,
                              void* d_out, int out_size, void* d_ws, size_t ws_size,
                              hipStream_t stream) {
    const int*   y_true = (const int*)d_in[0];
    const float* y_pred = (const float*)d_in[1];
    float*       out    = (float*)d_out;
    ctc_fb_kernel<<<dim3(Bc), dim3(128), 0, stream>>>(y_true, y_pred, out);
}

// Round 9
// 26.604 us; speedup vs baseline: 3.8477x; 1.1975x over previous
//
#include <hip/hip_runtime.h>

// CTC batch cost, B=256 T=512 C=256 L=64 (S=129).
// R9: producer/consumer wave split. 4 waves/block: wid0 = fwd DP consumer,
// wid1 = bwd DP consumer, wid2/3 = staging producers (fwd/bwd). Producers
// fill per-direction 48-slot LDS row rings via global_load_lds with counted
// vmcnt (never 0 mid-loop); raw s_barrier rendezvous per 8-row group (no
// auto-drain, unlike __syncthreads). Consumers issue NO VMEM -> the
// compiler's conservative LDS-DMA vmcnt waits before ds_read are no-ops
// (R8 lesson: in a single wave, that conservative drain re-serialized every
// group on full HBM latency; depth R7->R8 couldn't fix it).
// DP math: f64 linear domain, DPP wave shifts, log2-domain cut combine
// (verified absmax 0.0 in R6/R7/R8).

constexpr int Bc = 256;
constexpr int Tc = 512;
constexpr int Cc = 256;
constexpr int Lc = 64;
constexpr int NS = 48;          // ring slots per direction = 6 groups x 8 rows

#define EPSF (1e-7f)
#define NEGF (-1e30f)

__device__ __forceinline__ float flog2(float x) {
    float r; asm("v_log_f32 %0, %1" : "=v"(r) : "v"(x)); return r;
}
__device__ __forceinline__ float fexp2(float x) {
    float r; asm("v_exp_f32 %0, %1" : "=v"(r) : "v"(x)); return r;
}
__device__ __forceinline__ float lse2(float a, float b) {
    float m = fmaxf(a, b);
    float d = fminf(a, b) - m;
    return m + flog2(1.f + fexp2(d));
}
// log2 of a positive double via exponent extraction + f32 mantissa log.
__device__ __forceinline__ float dlog2(double x) {
    if (!(x > 1e-300)) return NEGF;
    const int hb = __double2hiint(x);
    const int lb = __double2loint(x);
    const int e  = ((hb >> 20) & 0x7FF) - 1022;
    const double m = __hiloint2double((hb & 0x800FFFFF) | (1022 << 20), lb);
    return flog2((float)m) + (float)e;            // m in [0.5, 1)
}
// double wave shifts via paired 32-bit DPP; 'old' fills the boundary lane.
__device__ __forceinline__ double dpp_up1_d(double old, double src) {   // lane i <- i-1
    const int rl = __builtin_amdgcn_update_dpp(
        __double2loint(old), __double2loint(src), 0x138, 0xF, 0xF, false);
    const int rh = __builtin_amdgcn_update_dpp(
        __double2hiint(old), __double2hiint(src), 0x138, 0xF, 0xF, false);
    return __hiloint2double(rh, rl);
}
__device__ __forceinline__ double dpp_dn1_d(double old, double src) {   // lane i <- i+1
    const int rl = __builtin_amdgcn_update_dpp(
        __double2loint(old), __double2loint(src), 0x130, 0xF, 0xF, false);
    const int rh = __builtin_amdgcn_update_dpp(
        __double2hiint(old), __double2hiint(src), 0x130, 0xF, 0xF, false);
    return __hiloint2double(rh, rl);
}
// async global->LDS: lane l writes bytes [16l,16l+16) of the 1 KB slot.
__device__ __forceinline__ void stage16(const float* g, float* l) {
    __builtin_amdgcn_global_load_lds(
        (const __attribute__((address_space(1))) void*)g,
        (__attribute__((address_space(3))) void*)l, 16, 0, 0);
}

__global__ __launch_bounds__(256, 1) void ctc_fb_kernel(
        const int* __restrict__ y_true,
        const float* __restrict__ y_pred,
        float* __restrict__ out)
{
    const int b    = blockIdx.x;
    const int lane = threadIdx.x & 63;
    const int wid  = threadIdx.x >> 6;
    const int dir  = wid & 1;

    __shared__ float ring[2][NS][Cc];       // 96 KB
    __shared__ float Cl[64], Ch[64];
    __shared__ float CexS;

    const float* __restrict__ bbase = y_pred + (size_t)b * Tc * Cc;

    double lo = 0.0, hi = 0.0, ex = 0.0;

    if (wid >= 2) {
        // ---------------- producer wave for direction 'dir' ----------------
        // local row u -> global row: fwd u, bwd 511-u.
        const float* __restrict__ g0 =
            dir ? (bbase + (size_t)(Tc - 1) * Cc + lane * 4)
                : (bbase + lane * 4);
        const ptrdiff_t stp = dir ? -(ptrdiff_t)Cc : (ptrdiff_t)Cc;
        float* const lds0 = &ring[dir][0][0];
        // prologue: rows 0..31 (groups 0..3) -> slots 0..31
        #pragma unroll
        for (int u = 0; u < 32; ++u)
            stage16(g0 + stp * u, lds0 + u * Cc);
        int sg = 32;                         // slot offset of group g+4
        for (int g = 0; g < 32; ++g) {
            if (g <= 27) {                   // stage group g+4 (rows 8g+32..39)
                const float* gb = g0 + stp * (8 * (g + 4));
                float* lb = lds0 + sg * Cc;
                #pragma unroll
                for (int j = 0; j < 8; ++j)
                    stage16(gb + stp * j, lb + j * Cc);
            }
            // guarantee group g landed: issued 8*(min(g+4,31)+1), need
            // retired >= 8*(g+1)  -> counted vmcnt, never early-drained.
            if (g <= 27)      asm volatile("s_waitcnt vmcnt(32)" ::: "memory");
            else if (g == 28) asm volatile("s_waitcnt vmcnt(24)" ::: "memory");
            else if (g == 29) asm volatile("s_waitcnt vmcnt(16)" ::: "memory");
            else if (g == 30) asm volatile("s_waitcnt vmcnt(8)"  ::: "memory");
            else              asm volatile("s_waitcnt vmcnt(0)"  ::: "memory");
            __builtin_amdgcn_s_barrier();    // rendezvous #g (raw: no drain)
            sg += 8; if (sg >= NS) sg = 0;
        }
    } else {
        // ---------------- consumer (DP) waves ----------------
        const int lab  = y_true[b * Lc + lane];
        const int labp = __shfl_up(lab, 1);
        const int labn = __shfl_down(lab, 1);

        if (wid == 0) {
            // forward DP: steps/rows 0..255
            const bool allowF = (lane >= 1) && (lab != labp);
            auto stepF = [&](float pBf, float pLf) {
                const double pB = (double)pBf, pL = (double)pLf;
                const double prevHi = dpp_up1_d(0.0, hi);
                const double sk  = allowF ? prevHi : 0.0;
                const double nlo = (lo + prevHi) * pB;
                const double nhi = (hi + lo + sk) * pL;
                ex = (ex + hi) * pB;     // real only at lane 63 (127->128)
                hi = nhi; lo = nlo;
            };
            int sb = 0;
            for (int g = 0; g < 32; ++g) {
                asm volatile("" ::: "memory");
                __builtin_amdgcn_s_barrier();        // group g ready
                asm volatile("" ::: "memory");
#define RDF(j) const float cL##j = ring[0][sb + j][lab] + EPSF, \
                           cB##j = ring[0][sb + j][Cc - 1] + EPSF;
                RDF(0) RDF(1) RDF(2) RDF(3) RDF(4) RDF(5) RDF(6) RDF(7)
#undef RDF
                if (g == 0) {
                    lo = (lane == 0) ? (double)cB0 : 0.0;    // alpha0(0)
                    hi = (lane == 0) ? (double)cL0 : 0.0;    // alpha0(1)
                } else stepF(cB0, cL0);
                stepF(cB1, cL1); stepF(cB2, cL2); stepF(cB3, cL3);
                stepF(cB4, cL4); stepF(cB5, cL5); stepF(cB6, cL6);
                stepF(cB7, cL7);
                sb += 8; if (sb >= NS) sb = 0;
            }
        } else {
            // backward DP: local rows 0..255 <-> t = 511..256
            const bool allowB = (lane < 63) && (labn != lab);
            auto stepB = [&](float pBf, float pLf) {
                const double pB = (double)pBf, pL = (double)pLf;
                const double nlo_s = dpp_dn1_d(ex, lo);   // B(2l+2); l63 <- ex
                const double nhi_s = dpp_dn1_d(0.0, hi);  // B(2l+3); l63 <- 0
                const double sk = allowB ? nhi_s : 0.0;
                const double l2 = (lo + hi) * pB;
                const double h2 = (hi + nlo_s + sk) * pL;
                ex = ex * pB;
                lo = l2; hi = h2;
            };
            int sb = 0;
            for (int g = 0; g < 32; ++g) {
                asm volatile("" ::: "memory");
                __builtin_amdgcn_s_barrier();        // group g ready
                asm volatile("" ::: "memory");
#define RDB(j) const float cL##j = ring[1][sb + j][lab] + EPSF, \
                           cB##j = ring[1][sb + j][Cc - 1] + EPSF;
                RDB(0) RDB(1) RDB(2) RDB(3) RDB(4) RDB(5) RDB(6) RDB(7)
#undef RDB
                if (g == 0) {
                    ex = (double)cB0;                          // beta511(128)
                    hi = (lane == 63) ? (double)cL0 : 0.0;     // beta511(127)
                    lo = 0.0;
                } else stepB(cB0, cL0);
                stepB(cB1, cL1); stepB(cB2, cL2); stepB(cB3, cL3);
                stepB(cB4, cL4); stepB(cB5, cL5); stepB(cB6, cL6);
                stepB(cB7, cL7);
                sb += 8; if (sb >= NS) sb = 0;
            }
            // cut combine half-step: C(s) = B(s) + B(s+1) + allowB(s)*B(s+2),
            // stored log2-domain (R4 lesson: anti-aligned maxima).
            const double nlo_s = dpp_dn1_d(ex, lo);
            const double nhi_s = dpp_dn1_d(0.0, hi);
            const double sk = allowB ? nhi_s : 0.0;
            Cl[lane] = dlog2(lo + hi);
            Ch[lane] = dlog2(hi + nlo_s + sk);
            if (lane == 63) CexS = dlog2(ex);
        }
    }

    __syncthreads();

    if (wid == 0) {
        const float w1 = dlog2(lo) + Cl[lane];
        const float w2 = dlog2(hi) + Ch[lane];
        float w = lse2(w1, w2);
        if (lane == 63) w = lse2(w, dlog2(ex) + CexS);
        #pragma unroll
        for (int off = 32; off; off >>= 1) w = lse2(w, __shfl_xor(w, off));
        if (lane == 0)
            out[b] = -0.69314718055994530942f * w;     // ln2 * log2 -> ln
    }
}

extern "C" void kernel_launch(void* const* d_in, const int* in_sizes, int n_in,
                              void* d_out, int out_size, void* d_ws, size_t ws_size,
                              hipStream_t stream) {
    const int*   y_true = (const int*)d_in[0];
    const float* y_pred = (const float*)d_in[1];
    float*       out    = (float*)d_out;
    ctc_fb_kernel<<<dim3(Bc), dim3(256), 0, stream>>>(y_true, y_pred, out);
}